// Round 3
// baseline (225.504 us; speedup 1.0000x reference)
//
#include <hip/hip_runtime.h>

#define NATOM   4096
#define NG4     (NATOM / 4)       // 1024 float4 groups per row
#define NBOND   6144
#define NANGLE  8192
#define NUB     4096
#define NDIH    12288
#define NIMP    2048

#define NB_BLOCKS   2048          // nonbonded: block b -> rows b and NATOM-1-b
#define BOND_ITEMS  (NBOND + NANGLE + NUB + NDIH + NIMP)   // 32768
#define BOND_WORKB  (BOND_ITEMS / 256)                      // 128
#define BOND_BLOCKS (BOND_WORKB + 1)                        // +1 block for central term
#define TOTAL_SLOTS (NB_BLOCKS + BOND_BLOCKS)               // 2177 doubles in d_ws

#define DEG2RAD 0.017453292519943295f

// ---- block reduction (sum of doubles), result valid on thread 0 ----
static __device__ __forceinline__ double block_reduce(double v, double* sm) {
    #pragma unroll
    for (int off = 32; off > 0; off >>= 1) v += __shfl_down(v, off, 64);
    const int lane = threadIdx.x & 63, wid = threadIdx.x >> 6;
    __syncthreads();                 // safe LDS reuse across successive calls
    if (lane == 0) sm[wid] = v;
    __syncthreads();
    double r = 0.0;
    if (threadIdx.x == 0) {
        const int nw = blockDim.x >> 6;
        for (int w = 0; w < nw; ++w) r += sm[w];
    }
    return r;
}

// one pair's vdW + electrostatic contribution (f32), predicated
static __device__ __forceinline__ float pair_term(
    float xi0, float xi1, float xi2,
    float xj0, float xj1, float xj2,
    float e, float r, float q, bool valid)
{
    const float dx = xi0 - xj0, dy = xi1 - xj1, dz = xi2 - xj2;
    float d2 = fmaf(dx, dx, fmaf(dy, dy, dz * dz));
    d2 = fmaxf(d2, 1e-12f);
    float inv = rsqrtf(d2);                       // ~1-2 ulp
    const float t = inv * inv;
    inv = inv * fmaf(-0.5f * d2, t, 1.5f);        // one Newton step -> ~0.5 ulp
    const float rod = r * inv;
    const float r2 = rod * rod;
    const float r6 = r2 * r2 * r2;
    const float v = fmaf(e * r6, r6 - 2.0f, q * inv);
    return valid ? v : 0.0f;
}

// process one float4-group of row `i` (coords of i given), f32 partial
static __device__ __forceinline__ float group_term(
    int i, float xi0, float xi1, float xi2, int g,
    float4 e, float4 r, float4 q, float4 xa, float4 xb, float4 xc)
{
    const int j0 = 4 * g;
    float s;
    s  = pair_term(xi0,xi1,xi2, xa.x,xa.y,xa.z, e.x,r.x,q.x, j0+0 > i);
    s += pair_term(xi0,xi1,xi2, xa.w,xb.x,xb.y, e.y,r.y,q.y, j0+1 > i);
    s += pair_term(xi0,xi1,xi2, xb.z,xb.w,xc.x, e.z,r.z,q.z, j0+2 > i);
    s += pair_term(xi0,xi1,xi2, xc.y,xc.z,xc.w, e.w,r.w,q.w, j0+3 > i);
    return s;
}

// ---------------- bonded terms ----------------
static __device__ __forceinline__ float torsion(const float* __restrict__ x,
                                                int i0, int i1, int i2, int i3) {
    const float ax = x[3*i1] - x[3*i0], ay = x[3*i1+1] - x[3*i0+1], az = x[3*i1+2] - x[3*i0+2];
    const float bx = x[3*i2] - x[3*i1], by = x[3*i2+1] - x[3*i1+1], bz = x[3*i2+2] - x[3*i1+2];
    const float cx = x[3*i3] - x[3*i2], cy = x[3*i3+1] - x[3*i2+1], cz = x[3*i3+2] - x[3*i2+2];
    const float n1x = ay*bz - az*by, n1y = az*bx - ax*bz, n1z = ax*by - ay*bx;
    const float n2x = by*cz - bz*cy, n2y = bz*cx - bx*cz, n2z = bx*cy - by*cx;
    const float dt  = n1x*n2x + n1y*n2y + n1z*n2z;
    const float nn1 = sqrtf(n1x*n1x + n1y*n1y + n1z*n1z);
    const float nn2 = sqrtf(n2x*n2x + n2y*n2y + n2z*n2z);
    float c = dt / (nn1 * nn2);
    c = fminf(fmaxf(c, -0.9999f), 0.9999f);
    const float ang = acosf(c);
    const float sx = n1y*n2z - n1z*n2y, sy = n1z*n2x - n1x*n2z, sz = n1x*n2y - n1y*n2x;
    const float s = sx*bx + sy*by + sz*bz;
    const float sg = (s > 0.0f) ? 1.0f : ((s < 0.0f) ? -1.0f : 0.0f);
    return ang * sg;
}

// ---------------- fused kernel: nb blocks [0,NB_BLOCKS), bonded after ----------------
__global__ __launch_bounds__(256) void ff_kernel(
    const float4* __restrict__ xv,
    const float4* __restrict__ eps,
    const float4* __restrict__ rmin,
    const float4* __restrict__ kqq,
    const float* __restrict__ kb, const float* __restrict__ b0,
    const float* __restrict__ kt, const float* __restrict__ t0,
    const float* __restrict__ ku, const float* __restrict__ s0,
    const float* __restrict__ kd, const float* __restrict__ nd, const float* __restrict__ d0,
    const float* __restrict__ kp, const float* __restrict__ p0,
    const int* __restrict__ bond, const int* __restrict__ angle,
    const int* __restrict__ ub,   const int* __restrict__ dih,
    const int* __restrict__ imp,  const int* __restrict__ central,
    double* __restrict__ ws)
{
    __shared__ double sm[4];
    const float* __restrict__ x = (const float*)xv;

    if (blockIdx.x < NB_BLOCKS) {
        // ---------------- nonbonded ----------------
        const int b  = (int)blockIdx.x;
        const int i0 = b, i1 = NATOM - 1 - b;
        const float xi00 = x[3*i0], xi01 = x[3*i0+1], xi02 = x[3*i0+2];
        const float xi10 = x[3*i1], xi11 = x[3*i1+1], xi12 = x[3*i1+2];
        const int ga = (i0 + 1) >> 2, gb = (i1 + 1) >> 2;
        const int c0 = NG4 - ga;              // groups in row i0
        const int c1 = NG4 - gb;              // groups in row i1
        const int total = c0 + c1;            // 1024 or 1025
        const int t = (int)threadIdx.x;

        // phase 0: map 4 consecutive virtual groups to (row, group)
        int  rw[4]; int gv[4]; bool lo[4];
        #pragma unroll
        for (int u = 0; u < 4; ++u) {
            const int v = 4 * t + u;          // 0..1023 < total always
            lo[u] = v < c0;
            rw[u] = lo[u] ? i0 : i1;
            gv[u] = lo[u] ? (ga + v) : (gb + v - c0);
        }
        // phase 1: issue ALL matrix loads back-to-back (independent, 12 x dwordx4)
        float4 le[4], lr[4], lq[4];
        #pragma unroll
        for (int u = 0; u < 4; ++u) {
            const size_t base = (size_t)rw[u] * NG4 + gv[u];
            le[u] = eps [base];
            lr[u] = rmin[base];
            lq[u] = kqq [base];
        }
        // phase 2: coords (L1/L2-resident) + math
        double acc = 0.0;
        #pragma unroll
        for (int u = 0; u < 4; ++u) {
            const int g3 = 3 * gv[u];
            const float4 xa = xv[g3], xb = xv[g3+1], xc = xv[g3+2];
            const float xi0c = lo[u] ? xi00 : xi10;
            const float xi1c = lo[u] ? xi01 : xi11;
            const float xi2c = lo[u] ? xi02 : xi12;
            acc += (double)group_term(rw[u], xi0c, xi1c, xi2c, gv[u],
                                      le[u], lr[u], lq[u], xa, xb, xc);
        }
        // leftover virtual group (total == 1025) -> thread 0, always row i1
        if (t == 0 && total == 1025) {
            const int g = gb + (1024 - c0);
            const size_t base = (size_t)i1 * NG4 + g;
            const int g3 = 3 * g;
            acc += (double)group_term(i1, xi10, xi11, xi12, g,
                                      eps[base], rmin[base], kqq[base],
                                      xv[g3], xv[g3+1], xv[g3+2]);
        }
        const double tot = block_reduce(acc, sm);
        if (t == 0) ws[blockIdx.x] = tot;
        return;
    }

    // ---------------- bonded ----------------
    const int bb = (int)blockIdx.x - NB_BLOCKS;

    if (bb == BOND_WORKB) {
        // central term: 0.1 * sum|x - mean|^2 = 0.1*(sum|x|^2 - |sum x|^2 / N)
        double out = 0.0;
        if (*central != 0) {
            double sx = 0.0, sy = 0.0, sz = 0.0, s2 = 0.0;
            for (int i = threadIdx.x; i < NATOM; i += 256) {
                const float a = x[3*i], b = x[3*i+1], c = x[3*i+2];
                sx += a; sy += b; sz += c;
                s2 += (double)a*a + (double)b*b + (double)c*c;
            }
            const double rx = block_reduce(sx, sm);
            const double ry = block_reduce(sy, sm);
            const double rz = block_reduce(sz, sm);
            const double r2 = block_reduce(s2, sm);
            if (threadIdx.x == 0)
                out = 0.1 * (r2 - (rx*rx + ry*ry + rz*rz) / (double)NATOM);
        }
        if (threadIdx.x == 0) ws[NB_BLOCKS + bb] = out;
        return;
    }

    const int t = bb * 256 + (int)threadIdx.x;
    double v = 0.0;

    if (t < NBOND) {
        const int m = t;
        const int i = bond[2*m], j = bond[2*m+1];
        const float dx = x[3*i]-x[3*j], dy = x[3*i+1]-x[3*j+1], dz = x[3*i+2]-x[3*j+2];
        const float dis = sqrtf(dx*dx + dy*dy + dz*dz);
        const float d = dis - b0[m];
        v = (double)(kb[m] * d * d);
    } else if (t < NBOND + NANGLE) {
        const int m = t - NBOND;
        const int i = angle[3*m], j = angle[3*m+1], k = angle[3*m+2];
        const float bax = x[3*i]-x[3*j], bay = x[3*i+1]-x[3*j+1], baz = x[3*i+2]-x[3*j+2];
        const float bcx = x[3*k]-x[3*j], bcy = x[3*k+1]-x[3*j+1], bcz = x[3*k+2]-x[3*j+2];
        const float dt  = bax*bcx + bay*bcy + baz*bcz;
        const float na  = sqrtf(bax*bax + bay*bay + baz*baz);
        const float nb  = sqrtf(bcx*bcx + bcy*bcy + bcz*bcz);
        float c = dt / (na * nb);
        c = fminf(fmaxf(c, -0.9999f), 0.9999f);
        const float theta = acosf(c);
        const float d = theta - t0[m] * DEG2RAD;
        v = (double)(kt[m] * d * d);
    } else if (t < NBOND + NANGLE + NUB) {
        const int m = t - NBOND - NANGLE;
        const int i = ub[2*m], j = ub[2*m+1];
        const float dx = x[3*i]-x[3*j], dy = x[3*i+1]-x[3*j+1], dz = x[3*i+2]-x[3*j+2];
        const float dis = sqrtf(dx*dx + dy*dy + dz*dz);
        const float d = dis - s0[m];
        v = (double)(ku[m] * d * d);
    } else if (t < NBOND + NANGLE + NUB + NDIH) {
        const int m = t - NBOND - NANGLE - NUB;
        const float delta = torsion(x, dih[4*m], dih[4*m+1], dih[4*m+2], dih[4*m+3]);
        v = (double)(kd[m] * (1.0f + cosf(nd[m] * delta - d0[m] * DEG2RAD)));
    } else {
        const int m = t - NBOND - NANGLE - NUB - NDIH;
        const float psi = torsion(x, imp[4*m], imp[4*m+1], imp[4*m+2], imp[4*m+3]);
        const float d = psi - p0[m] * DEG2RAD;
        v = (double)(kp[m] * d * d);
    }

    const double tot = block_reduce(v, sm);
    if (threadIdx.x == 0) ws[NB_BLOCKS + bb] = tot;
}

// ---------------- finalize: sum all partials, write f32 scalar ----------------
__global__ __launch_bounds__(256) void finalize_kernel(const double* __restrict__ ws,
                                                       float* __restrict__ out) {
    __shared__ double sm[4];
    double v = 0.0;
    for (int i = threadIdx.x; i < TOTAL_SLOTS; i += 256) v += ws[i];
    const double tot = block_reduce(v, sm);
    if (threadIdx.x == 0) out[0] = (float)tot;
}

extern "C" void kernel_launch(void* const* d_in, const int* in_sizes, int n_in,
                              void* d_out, int out_size, void* d_ws, size_t ws_size,
                              hipStream_t stream) {
    const float* x    = (const float*)d_in[0];
    const float* kb   = (const float*)d_in[1];
    const float* b0   = (const float*)d_in[2];
    const float* kt   = (const float*)d_in[3];
    const float* t0   = (const float*)d_in[4];
    const float* ku   = (const float*)d_in[5];
    const float* s0   = (const float*)d_in[6];
    const float* kd   = (const float*)d_in[7];
    const float* nd   = (const float*)d_in[8];
    const float* d0   = (const float*)d_in[9];
    const float* kp   = (const float*)d_in[10];
    const float* p0   = (const float*)d_in[11];
    const float* eps  = (const float*)d_in[12];
    const float* rmin = (const float*)d_in[13];
    const float* kqq  = (const float*)d_in[14];
    const int* bond   = (const int*)d_in[15];
    const int* angle  = (const int*)d_in[16];
    const int* ub     = (const int*)d_in[17];
    const int* dih    = (const int*)d_in[18];
    const int* imp    = (const int*)d_in[19];
    const int* cent   = (const int*)d_in[20];

    double* ws = (double*)d_ws;

    ff_kernel<<<NB_BLOCKS + BOND_BLOCKS, 256, 0, stream>>>(
        (const float4*)x, (const float4*)eps, (const float4*)rmin, (const float4*)kqq,
        kb, b0, kt, t0, ku, s0, kd, nd, d0, kp, p0,
        bond, angle, ub, dih, imp, cent, ws);
    finalize_kernel<<<1, 256, 0, stream>>>(ws, (float*)d_out);
}

// Round 4
// 215.264 us; speedup vs baseline: 1.0476x; 1.0476x over previous
//
#include <hip/hip_runtime.h>

#define NATOM   4096
#define NG4     (NATOM / 4)       // 1024 float4 groups per row
#define NBOND   6144
#define NANGLE  8192
#define NUB     4096
#define NDIH    12288
#define NIMP    2048

#define NB_BLOCKS   2048          // nonbonded: block b -> rows b and NATOM-1-b
#define BOND_ITEMS  (NBOND + NANGLE + NUB + NDIH + NIMP)   // 32768
#define BOND_WORKB  (BOND_ITEMS / 256)                      // 128
#define BOND_BLOCKS (BOND_WORKB + 1)                        // +1 block for central term
#define TOTAL_SLOTS (NB_BLOCKS + BOND_BLOCKS)               // 2177 doubles in d_ws

#define DEG2RAD 0.017453292519943295f

// ---- block reduction (sum of doubles), result valid on thread 0 ----
static __device__ __forceinline__ double block_reduce(double v, double* sm) {
    #pragma unroll
    for (int off = 32; off > 0; off >>= 1) v += __shfl_down(v, off, 64);
    const int lane = threadIdx.x & 63, wid = threadIdx.x >> 6;
    __syncthreads();                 // safe LDS reuse across successive calls
    if (lane == 0) sm[wid] = v;
    __syncthreads();
    double r = 0.0;
    if (threadIdx.x == 0) {
        const int nw = blockDim.x >> 6;
        for (int w = 0; w < nw; ++w) r += sm[w];
    }
    return r;
}

// one pair's vdW + electrostatic contribution (f32), predicated
static __device__ __forceinline__ float pair_term(
    float xi0, float xi1, float xi2,
    float xj0, float xj1, float xj2,
    float e, float r, float q, bool valid)
{
    const float dx = xi0 - xj0, dy = xi1 - xj1, dz = xi2 - xj2;
    float d2 = fmaf(dx, dx, fmaf(dy, dy, dz * dz));
    d2 = fmaxf(d2, 1e-12f);
    float inv = rsqrtf(d2);                       // ~1-2 ulp
    const float t = inv * inv;
    inv = inv * fmaf(-0.5f * d2, t, 1.5f);        // one Newton step -> ~0.5 ulp
    const float rod = r * inv;
    const float r2 = rod * rod;
    const float r6 = r2 * r2 * r2;
    const float v = fmaf(e * r6, r6 - 2.0f, q * inv);
    return valid ? v : 0.0f;
}

// process one float4-group of row `i` (coords of i given), f32 partial
static __device__ __forceinline__ float group_term(
    int i, float xi0, float xi1, float xi2, int g,
    float4 e, float4 r, float4 q, float4 xa, float4 xb, float4 xc)
{
    const int j0 = 4 * g;
    float s;
    s  = pair_term(xi0,xi1,xi2, xa.x,xa.y,xa.z, e.x,r.x,q.x, j0+0 > i);
    s += pair_term(xi0,xi1,xi2, xa.w,xb.x,xb.y, e.y,r.y,q.y, j0+1 > i);
    s += pair_term(xi0,xi1,xi2, xb.z,xb.w,xc.x, e.z,r.z,q.z, j0+2 > i);
    s += pair_term(xi0,xi1,xi2, xc.y,xc.z,xc.w, e.w,r.w,q.w, j0+3 > i);
    return s;
}

// ---------------- bonded terms ----------------
static __device__ __forceinline__ float torsion(const float* __restrict__ x,
                                                int i0, int i1, int i2, int i3) {
    const float ax = x[3*i1] - x[3*i0], ay = x[3*i1+1] - x[3*i0+1], az = x[3*i1+2] - x[3*i0+2];
    const float bx = x[3*i2] - x[3*i1], by = x[3*i2+1] - x[3*i1+1], bz = x[3*i2+2] - x[3*i1+2];
    const float cx = x[3*i3] - x[3*i2], cy = x[3*i3+1] - x[3*i2+1], cz = x[3*i3+2] - x[3*i2+2];
    const float n1x = ay*bz - az*by, n1y = az*bx - ax*bz, n1z = ax*by - ay*bx;
    const float n2x = by*cz - bz*cy, n2y = bz*cx - bx*cz, n2z = bx*cy - by*cx;
    const float dt  = n1x*n2x + n1y*n2y + n1z*n2z;
    const float nn1 = sqrtf(n1x*n1x + n1y*n1y + n1z*n1z);
    const float nn2 = sqrtf(n2x*n2x + n2y*n2y + n2z*n2z);
    float c = dt / (nn1 * nn2);
    c = fminf(fmaxf(c, -0.9999f), 0.9999f);
    const float ang = acosf(c);
    const float sx = n1y*n2z - n1z*n2y, sy = n1z*n2x - n1x*n2z, sz = n1x*n2y - n1y*n2x;
    const float s = sx*bx + sy*by + sz*bz;
    const float sg = (s > 0.0f) ? 1.0f : ((s < 0.0f) ? -1.0f : 0.0f);
    return ang * sg;
}

// ---------------- fused kernel: nb blocks [0,NB_BLOCKS), bonded after ----------------
__global__ __launch_bounds__(256) void ff_kernel(
    const float4* __restrict__ xv,
    const float4* __restrict__ eps,
    const float4* __restrict__ rmin,
    const float4* __restrict__ kqq,
    const float* __restrict__ kb, const float* __restrict__ b0,
    const float* __restrict__ kt, const float* __restrict__ t0,
    const float* __restrict__ ku, const float* __restrict__ s0,
    const float* __restrict__ kd, const float* __restrict__ nd, const float* __restrict__ d0,
    const float* __restrict__ kp, const float* __restrict__ p0,
    const int* __restrict__ bond, const int* __restrict__ angle,
    const int* __restrict__ ub,   const int* __restrict__ dih,
    const int* __restrict__ imp,  const int* __restrict__ central,
    double* __restrict__ ws)
{
    __shared__ double sm[4];
    const float* __restrict__ x = (const float*)xv;

    if (blockIdx.x < NB_BLOCKS) {
        // ---------------- nonbonded ----------------
        const int b = (int)blockIdx.x;
        const int t = (int)threadIdx.x;
        double acc = 0.0;
        #pragma unroll
        for (int half = 0; half < 2; ++half) {
            const int i = half ? (NATOM - 1 - b) : b;
            const float xi0 = x[3*i], xi1 = x[3*i+1], xi2 = x[3*i+2];
            const int g0 = (i + 1) >> 2;
            const size_t rowbase = (size_t)i * NG4;

            // thread t handles groups g0 + t + 256*u, u=0..3 (coalesced per u).
            // Clamp out-of-range to NG4-1 (uniform broadcast line), zero later.
            int gs[4]; bool ok[4];
            #pragma unroll
            for (int u = 0; u < 4; ++u) {
                const int g = g0 + t + (u << 8);
                ok[u] = (g < NG4);
                gs[u] = ok[u] ? g : (NG4 - 1);
            }
            // phase A: 12 independent coalesced loads back-to-back
            float4 le[4], lr[4], lq[4];
            #pragma unroll
            for (int u = 0; u < 4; ++u) le[u] = eps [rowbase + gs[u]];
            #pragma unroll
            for (int u = 0; u < 4; ++u) lr[u] = rmin[rowbase + gs[u]];
            #pragma unroll
            for (int u = 0; u < 4; ++u) lq[u] = kqq [rowbase + gs[u]];
            // phase B: coords (L1/L2-hot) + math
            #pragma unroll
            for (int u = 0; u < 4; ++u) {
                const int g3 = 3 * gs[u];
                const float4 xa = xv[g3], xb = xv[g3+1], xc = xv[g3+2];
                const float s = group_term(i, xi0, xi1, xi2, gs[u],
                                           le[u], lr[u], lq[u], xa, xb, xc);
                acc += (double)(ok[u] ? s : 0.0f);
            }
        }
        const double tot = block_reduce(acc, sm);
        if (t == 0) ws[blockIdx.x] = tot;
        return;
    }

    // ---------------- bonded ----------------
    const int bb = (int)blockIdx.x - NB_BLOCKS;

    if (bb == BOND_WORKB) {
        // central term: 0.1 * sum|x - mean|^2 = 0.1*(sum|x|^2 - |sum x|^2 / N)
        double out = 0.0;
        if (*central != 0) {
            double sx = 0.0, sy = 0.0, sz = 0.0, s2 = 0.0;
            for (int i = threadIdx.x; i < NATOM; i += 256) {
                const float a = x[3*i], b = x[3*i+1], c = x[3*i+2];
                sx += a; sy += b; sz += c;
                s2 += (double)a*a + (double)b*b + (double)c*c;
            }
            const double rx = block_reduce(sx, sm);
            const double ry = block_reduce(sy, sm);
            const double rz = block_reduce(sz, sm);
            const double r2 = block_reduce(s2, sm);
            if (threadIdx.x == 0)
                out = 0.1 * (r2 - (rx*rx + ry*ry + rz*rz) / (double)NATOM);
        }
        if (threadIdx.x == 0) ws[NB_BLOCKS + bb] = out;
        return;
    }

    const int t = bb * 256 + (int)threadIdx.x;
    double v = 0.0;

    if (t < NBOND) {
        const int m = t;
        const int i = bond[2*m], j = bond[2*m+1];
        const float dx = x[3*i]-x[3*j], dy = x[3*i+1]-x[3*j+1], dz = x[3*i+2]-x[3*j+2];
        const float dis = sqrtf(dx*dx + dy*dy + dz*dz);
        const float d = dis - b0[m];
        v = (double)(kb[m] * d * d);
    } else if (t < NBOND + NANGLE) {
        const int m = t - NBOND;
        const int i = angle[3*m], j = angle[3*m+1], k = angle[3*m+2];
        const float bax = x[3*i]-x[3*j], bay = x[3*i+1]-x[3*j+1], baz = x[3*i+2]-x[3*j+2];
        const float bcx = x[3*k]-x[3*j], bcy = x[3*k+1]-x[3*j+1], bcz = x[3*k+2]-x[3*j+2];
        const float dt  = bax*bcx + bay*bcy + baz*bcz;
        const float na  = sqrtf(bax*bax + bay*bay + baz*baz);
        const float nb  = sqrtf(bcx*bcx + bcy*bcy + bcz*bcz);
        float c = dt / (na * nb);
        c = fminf(fmaxf(c, -0.9999f), 0.9999f);
        const float theta = acosf(c);
        const float d = theta - t0[m] * DEG2RAD;
        v = (double)(kt[m] * d * d);
    } else if (t < NBOND + NANGLE + NUB) {
        const int m = t - NBOND - NANGLE;
        const int i = ub[2*m], j = ub[2*m+1];
        const float dx = x[3*i]-x[3*j], dy = x[3*i+1]-x[3*j+1], dz = x[3*i+2]-x[3*j+2];
        const float dis = sqrtf(dx*dx + dy*dy + dz*dz);
        const float d = dis - s0[m];
        v = (double)(ku[m] * d * d);
    } else if (t < NBOND + NANGLE + NUB + NDIH) {
        const int m = t - NBOND - NANGLE - NUB;
        const float delta = torsion(x, dih[4*m], dih[4*m+1], dih[4*m+2], dih[4*m+3]);
        v = (double)(kd[m] * (1.0f + cosf(nd[m] * delta - d0[m] * DEG2RAD)));
    } else {
        const int m = t - NBOND - NANGLE - NUB - NDIH;
        const float psi = torsion(x, imp[4*m], imp[4*m+1], imp[4*m+2], imp[4*m+3]);
        const float d = psi - p0[m] * DEG2RAD;
        v = (double)(kp[m] * d * d);
    }

    const double tot = block_reduce(v, sm);
    if (threadIdx.x == 0) ws[NB_BLOCKS + bb] = tot;
}

// ---------------- finalize: sum all partials, write f32 scalar ----------------
__global__ __launch_bounds__(256) void finalize_kernel(const double* __restrict__ ws,
                                                       float* __restrict__ out) {
    __shared__ double sm[4];
    double v = 0.0;
    for (int i = threadIdx.x; i < TOTAL_SLOTS; i += 256) v += ws[i];
    const double tot = block_reduce(v, sm);
    if (threadIdx.x == 0) out[0] = (float)tot;
}

extern "C" void kernel_launch(void* const* d_in, const int* in_sizes, int n_in,
                              void* d_out, int out_size, void* d_ws, size_t ws_size,
                              hipStream_t stream) {
    const float* x    = (const float*)d_in[0];
    const float* kb   = (const float*)d_in[1];
    const float* b0   = (const float*)d_in[2];
    const float* kt   = (const float*)d_in[3];
    const float* t0   = (const float*)d_in[4];
    const float* ku   = (const float*)d_in[5];
    const float* s0   = (const float*)d_in[6];
    const float* kd   = (const float*)d_in[7];
    const float* nd   = (const float*)d_in[8];
    const float* d0   = (const float*)d_in[9];
    const float* kp   = (const float*)d_in[10];
    const float* p0   = (const float*)d_in[11];
    const float* eps  = (const float*)d_in[12];
    const float* rmin = (const float*)d_in[13];
    const float* kqq  = (const float*)d_in[14];
    const int* bond   = (const int*)d_in[15];
    const int* angle  = (const int*)d_in[16];
    const int* ub     = (const int*)d_in[17];
    const int* dih    = (const int*)d_in[18];
    const int* imp    = (const int*)d_in[19];
    const int* cent   = (const int*)d_in[20];

    double* ws = (double*)d_ws;

    ff_kernel<<<NB_BLOCKS + BOND_BLOCKS, 256, 0, stream>>>(
        (const float4*)x, (const float4*)eps, (const float4*)rmin, (const float4*)kqq,
        kb, b0, kt, t0, ku, s0, kd, nd, d0, kp, p0,
        bond, angle, ub, dih, imp, cent, ws);
    finalize_kernel<<<1, 256, 0, stream>>>(ws, (float*)d_out);
}